// Round 4
// baseline (650.458 us; speedup 1.0000x reference)
//
#include <hip/hip_runtime.h>

// Transformer block fwd: B=128, T=256, E=512, H=8, D=64, F=2048, fp32 in/out.
// bf16 MFMA everywhere (abs threshold 0.109 >> bf16 error ~0.03), fp32 residual.
// R4 = R3 resubmission (R3 bench was an infra failure: container acquire died;
// kernel audited for hangs/faults — none found).
// GEMM: 3-buffer counted-vmcnt pipeline (T3/T4), BM=128 BN=256 BK=64, 512 thr,
// T2 XOR-swizzled LDS (pre-swizzled global src, rule 21), setprio (T5),
// XCD-bijective swizzle (T1).

typedef unsigned short u16;
typedef short short8 __attribute__((ext_vector_type(8)));
typedef float f32x4 __attribute__((ext_vector_type(4)));

#define BB 128
#define TT 256
#define EE 512
#define HH 8
#define DD 64
#define FF 2048
#define BT (BB * TT)          // 32768 rows

__device__ __forceinline__ u16 f2b(float f) {
  union { float f; unsigned int u; } v; v.f = f;
  unsigned int u = v.u + 0x7fffu + ((v.u >> 16) & 1u);   // RNE
  return (u16)(u >> 16);
}

__device__ __forceinline__ f32x4 mfma16(short8 a, short8 b, f32x4 c) {
  return __builtin_amdgcn_mfma_f32_16x16x32_bf16(a, b, c, 0, 0, 0);
}

// async global->LDS, 16B per lane; LDS dest = wave-uniform base + lane*16
__device__ __forceinline__ void g2l16(const u16* g, u16* l) {
  __builtin_amdgcn_global_load_lds(
      (const __attribute__((address_space(1))) unsigned int*)g,
      (__attribute__((address_space(3))) unsigned int*)l, 16, 0, 0);
}

// ---------------- tiled transpose + f32->bf16 ----------------

__global__ __launch_bounds__(256) void tconv(const float* __restrict__ src, int srs,
                                             u16* __restrict__ dst, int drs) {
  __shared__ u16 tile[64][67];
  const int r0 = blockIdx.x * 64, c0 = blockIdx.y * 64;
  const int tlo = threadIdx.x & 63, thi = threadIdx.x >> 6;
#pragma unroll
  for (int i = 0; i < 16; i++) {
    const int r = i * 4 + thi;
    tile[r][tlo] = f2b(src[(size_t)(r0 + r) * srs + c0 + tlo]);
  }
  __syncthreads();
#pragma unroll
  for (int i = 0; i < 16; i++) {
    const int c = i * 4 + thi;
    dst[(size_t)(c0 + c) * drs + r0 + tlo] = tile[tlo][c];
  }
}

// W [H][E][D] -> dst rows n = nbase + h*64 + d, cols e (drs = 512)
__global__ __launch_bounds__(256) void tconv_qkv(const float* __restrict__ W,
                                                 u16* __restrict__ dst0, int nbase) {
  __shared__ u16 tile[64][67];
  const int h = blockIdx.z;
  const float* src = W + (size_t)h * EE * DD;            // [E][D]
  u16* dst = dst0 + (size_t)(nbase + h * 64) * EE;
  const int r0 = blockIdx.x * 64;                        // e-tile
  const int tlo = threadIdx.x & 63, thi = threadIdx.x >> 6;
#pragma unroll
  for (int i = 0; i < 16; i++) {
    const int r = i * 4 + thi;
    tile[r][tlo] = f2b(src[(size_t)(r0 + r) * DD + tlo]);
  }
  __syncthreads();
#pragma unroll
  for (int i = 0; i < 16; i++) {
    const int d = i * 4 + thi;
    dst[(size_t)d * EE + r0 + tlo] = tile[tlo][d];
  }
}

// ---------------- LayerNorm: fp32 in -> bf16 out, one wave per row (E=512) -------

__global__ __launch_bounds__(256) void ln_fwd(const float* __restrict__ xin,
                                              const float* __restrict__ g,
                                              const float* __restrict__ bb,
                                              u16* __restrict__ out) {
  const int wid = threadIdx.x >> 6, lane = threadIdx.x & 63;
  const size_t row = (size_t)blockIdx.x * 4 + wid;
  const float* xr = xin + row * EE + lane * 8;
  float v[8];
  *(float4*)(v)     = *(const float4*)(xr);
  *(float4*)(v + 4) = *(const float4*)(xr + 4);
  float s = 0.f;
#pragma unroll
  for (int j = 0; j < 8; j++) s += v[j];
#pragma unroll
  for (int d = 1; d < 64; d <<= 1) s += __shfl_xor(s, d);
  const float mu = s * (1.f / 512.f);
  float q = 0.f;
#pragma unroll
  for (int j = 0; j < 8; j++) { float dd = v[j] - mu; q += dd * dd; }
#pragma unroll
  for (int d = 1; d < 64; d <<= 1) q += __shfl_xor(q, d);
  const float rstd = rsqrtf(q * (1.f / 512.f) + 1e-5f);
  float gv[8], bv[8];
  *(float4*)(gv)     = *(const float4*)(g + lane * 8);
  *(float4*)(gv + 4) = *(const float4*)(g + lane * 8 + 4);
  *(float4*)(bv)     = *(const float4*)(bb + lane * 8);
  *(float4*)(bv + 4) = *(const float4*)(bb + lane * 8 + 4);
  short8 o;
#pragma unroll
  for (int j = 0; j < 8; j++) o[j] = (short)f2b((v[j] - mu) * rstd * gv[j] + bv[j]);
  *(short8*)(out + row * EE + lane * 8) = o;
}

// ---------------- GEMM: 3-buffer counted-vmcnt pipeline ----------------
// C[M,N] = A[M,K] @ Bt[N,K]^T, bf16 in, fp32 acc.
// BM=128 BN=256 BK=64; 512 thr = 8 waves (2M x 4N), 64x64 per wave.
// LDS: 3 K-tile buffers (A 16KB + B 32KB each) = 144 KB, 1 block/CU.
// Per tile: vmcnt(6) + s_barrier (tile t's 6 loads done, t+1's stay in flight),
// then 2 k-slice phases: {issue 3 loads of t+2, 8 swizzled ds_read_b128,
// setprio(1), 16 MFMA, setprio(0)}. Loads have 2 full K-tiles to land.
// vmcnt is per-wave: each wave's 6 loads/tile cover exactly its own LDS slice,
// so own-wait-then-barrier => whole tile resident.
// T2 swizzle: LDS physical byte (row*128+pb) holds global col (pb ^ ((row&7)<<4));
// reads apply the same XOR => conflict-minimal ds_read_b128.

template <bool BIAS, bool RELU, bool RES, bool OUTBF>
__global__ __launch_bounds__(512, 2) void gemm3(const u16* __restrict__ A,
                                                const u16* __restrict__ Bt,
                                                const float* __restrict__ bias,
                                                const float* __restrict__ res,
                                                void* __restrict__ out,
                                                int M, int N, int K) {
  __shared__ __align__(16) u16 As[3 * 128 * 64];   // 48 KB
  __shared__ __align__(16) u16 Bs[3 * 256 * 64];   // 96 KB
  const int tid = threadIdx.x;
  const int wid = tid >> 6, lane = tid & 63;
  const int llo = lane & 15, lhi = lane >> 4;
  const int wrow = (wid >> 2) * 64;                // warp_m * 64
  const int wcol = (wid & 3) * 64;                 // warp_n * 64

  const int gx = N >> 8;                           // N / 256
  const int nwg = gx * (M >> 7);
  int id = blockIdx.x;
  id = (id & 7) * (nwg >> 3) + (id >> 3);          // XCD-bijective (nwg % 8 == 0)
  const size_t row0 = (size_t)(id / gx) * 128;
  const size_t col0 = (size_t)(id % gx) * 256;
  const int nt = K >> 6;

  auto stageA = [&](int tt, int c) {
    const int o = c * 8192 + tid * 16;                       // byte off in 16KB tile
    const int row = o >> 7;
    const int colb = (o & 127) ^ ((row & 7) << 4);
    g2l16(A + (row0 + row) * (size_t)K + (size_t)(tt << 6) + (colb >> 1),
          As + (tt % 3) * 8192 + c * 4096 + (wid << 9));
  };
  auto stageB = [&](int tt, int c) {
    const int o = c * 8192 + tid * 16;                       // byte off in 32KB tile
    const int row = o >> 7;
    const int colb = (o & 127) ^ ((row & 7) << 4);
    g2l16(Bt + (col0 + row) * (size_t)K + (size_t)(tt << 6) + (colb >> 1),
          Bs + (tt % 3) * 16384 + c * 4096 + (wid << 9));
  };

  f32x4 acc[4][4];
#pragma unroll
  for (int m = 0; m < 4; m++)
#pragma unroll
    for (int n = 0; n < 4; n++) acc[m][n] = (f32x4){0.f, 0.f, 0.f, 0.f};

  // prologue: stage tiles 0 and 1 (12 loads in flight per wave)
#pragma unroll
  for (int c = 0; c < 2; c++) stageA(0, c);
#pragma unroll
  for (int c = 0; c < 4; c++) stageB(0, c);
#pragma unroll
  for (int c = 0; c < 2; c++) stageA(1, c);
#pragma unroll
  for (int c = 0; c < 4; c++) stageB(1, c);

  for (int t = 0; t < nt; ++t) {
    if (t + 1 < nt) asm volatile("s_waitcnt vmcnt(6)" ::: "memory");
    else            asm volatile("s_waitcnt vmcnt(0)" ::: "memory");
    __builtin_amdgcn_s_barrier();
    asm volatile("" ::: "memory");
    const char* Ab = (const char*)As + (t % 3) * 16384;
    const char* Bb = (const char*)Bs + (t % 3) * 32768;
    const bool pf = (t + 2 < nt);

    // ---- phase 0: k-slice 0 ----
    if (pf) { stageA(t + 2, 0); stageA(t + 2, 1); stageB(t + 2, 0); }
    short8 a0[4], b0[4];
#pragma unroll
    for (int m = 0; m < 4; m++) {
      const int row = wrow + m * 16 + llo;
      a0[m] = *(const short8*)(Ab + row * 128 + ((lhi * 16) ^ ((row & 7) << 4)));
    }
#pragma unroll
    for (int n = 0; n < 4; n++) {
      const int row = wcol + n * 16 + llo;
      b0[n] = *(const short8*)(Bb + row * 128 + ((lhi * 16) ^ ((row & 7) << 4)));
    }
    __builtin_amdgcn_s_setprio(1);
#pragma unroll
    for (int m = 0; m < 4; m++)
#pragma unroll
      for (int n = 0; n < 4; n++) acc[m][n] = mfma16(a0[m], b0[n], acc[m][n]);
    __builtin_amdgcn_s_setprio(0);

    // ---- phase 1: k-slice 1 ----
    if (pf) { stageB(t + 2, 1); stageB(t + 2, 2); stageB(t + 2, 3); }
    short8 a1[4], b1[4];
#pragma unroll
    for (int m = 0; m < 4; m++) {
      const int row = wrow + m * 16 + llo;
      a1[m] = *(const short8*)(Ab + row * 128 + ((64 + lhi * 16) ^ ((row & 7) << 4)));
    }
#pragma unroll
    for (int n = 0; n < 4; n++) {
      const int row = wcol + n * 16 + llo;
      b1[n] = *(const short8*)(Bb + row * 128 + ((64 + lhi * 16) ^ ((row & 7) << 4)));
    }
    __builtin_amdgcn_s_setprio(1);
#pragma unroll
    for (int m = 0; m < 4; m++)
#pragma unroll
      for (int n = 0; n < 4; n++) acc[m][n] = mfma16(a1[m], b1[n], acc[m][n]);
    __builtin_amdgcn_s_setprio(0);
  }

  // epilogue
#pragma unroll
  for (int m = 0; m < 4; m++)
#pragma unroll
    for (int r = 0; r < 4; r++) {
      const size_t row = row0 + wrow + m * 16 + lhi * 4 + r;
#pragma unroll
      for (int n = 0; n < 4; n++) {
        const size_t col = col0 + wcol + n * 16 + llo;
        float v = acc[m][n][r];
        if (BIAS) v += bias[col];
        if (RELU) v = fmaxf(v, 0.f);
        if (RES) v += res[row * (size_t)N + col];
        if (OUTBF) ((u16*)out)[row * (size_t)N + col] = f2b(v);
        else       ((float*)out)[row * (size_t)N + col] = v;
      }
    }
}

// ---------------- Flash attention: one block per (b,h), wave w = Q rows [64w,64w+64) ----
// qkv [BT][1536] bf16 (q|k|v each 512 cols, head h at h*64). ctx [BT][512] bf16.

__global__ __launch_bounds__(256) void attn_fwd(const u16* __restrict__ qkv,
                                                u16* __restrict__ ctx) {
  const int bh = blockIdx.x;                 // 0..1023
  const int b = bh >> 3, h = bh & 7;
  const int wid = threadIdx.x >> 6;
  const int lane = threadIdx.x & 63;
  const int llo = lane & 15, lhi = lane >> 4;
  const int t0 = wid * 64;

  __shared__ u16 Vt[64][264];                // V^T [d][s], padded (33.8 KB)
  __shared__ u16 Pl[4][64][32];              // per-wave P staging (16 KB)

  const u16* qp = qkv + (size_t)b * TT * 1536 + h * 64;
  const u16* kp = qp + 512;
  const u16* vp = qp + 1024;

  // stage V^T
  {
    const int j = lane & 7;
#pragma unroll
    for (int g8 = 0; g8 < 8; g8++) {
      const int s = wid * 64 + g8 * 8 + (lane >> 3);
      const short8 v = *(const short8*)(vp + (size_t)s * 1536 + j * 8);
#pragma unroll
      for (int jj = 0; jj < 8; jj++) Vt[j * 8 + jj][s] = (u16)v[jj];
    }
  }

  short8 qf[4][2];
#pragma unroll
  for (int m = 0; m < 4; m++)
#pragma unroll
    for (int k2 = 0; k2 < 2; k2++) {
      const int t = t0 + m * 16 + llo;
      qf[m][k2] = *(const short8*)(qp + (size_t)t * 1536 + k2 * 32 + lhi * 8);
    }

  f32x4 O[4][4];
  float mrow[4][4], lrow[4][4];
#pragma unroll
  for (int m = 0; m < 4; m++) {
#pragma unroll
    for (int n = 0; n < 4; n++) O[m][n] = (f32x4){0.f, 0.f, 0.f, 0.f};
#pragma unroll
    for (int r = 0; r < 4; r++) { mrow[m][r] = -1e30f; lrow[m][r] = 0.f; }
  }

  __syncthreads();                            // Vt ready

  const int nst = (t0 + 64) >> 5;             // causal: s-tiles of 32
  for (int st = 0; st < nst; st++) {
    const int s0 = st * 32;
    f32x4 S[4][2];
#pragma unroll
    for (int m = 0; m < 4; m++) {
      S[m][0] = (f32x4){0.f, 0.f, 0.f, 0.f};
      S[m][1] = (f32x4){0.f, 0.f, 0.f, 0.f};
    }
#pragma unroll
    for (int k2 = 0; k2 < 2; k2++) {
      const short8 b0 = *(const short8*)(kp + (size_t)(s0 + llo) * 1536 + k2 * 32 + lhi * 8);
      const short8 b1 = *(const short8*)(kp + (size_t)(s0 + 16 + llo) * 1536 + k2 * 32 + lhi * 8);
#pragma unroll
      for (int m = 0; m < 4; m++) {
        S[m][0] = mfma16(qf[m][k2], b0, S[m][0]);
        S[m][1] = mfma16(qf[m][k2], b1, S[m][1]);
      }
    }
#pragma unroll
    for (int m = 0; m < 4; m++) {
      float sf[4];
#pragma unroll
      for (int r = 0; r < 4; r++) {
        const int t = t0 + m * 16 + lhi * 4 + r;
        float v0 = S[m][0][r] * 0.125f;
        float v1 = S[m][1][r] * 0.125f;
        if (s0 + llo > t)      v0 = -1e30f;
        if (s0 + 16 + llo > t) v1 = -1e30f;
        float mx = fmaxf(v0, v1);
#pragma unroll
        for (int d = 1; d < 16; d <<= 1) mx = fmaxf(mx, __shfl_xor(mx, d));
        const float mnew = fmaxf(mrow[m][r], mx);
        const float sc = __expf(mrow[m][r] - mnew);
        mrow[m][r] = mnew;
        const float p0 = __expf(v0 - mnew);
        const float p1 = __expf(v1 - mnew);
        float rs = p0 + p1;
#pragma unroll
        for (int d = 1; d < 16; d <<= 1) rs += __shfl_xor(rs, d);
        lrow[m][r] = lrow[m][r] * sc + rs;
        sf[r] = sc;
        const int pr = m * 16 + lhi * 4 + r;
        Pl[wid][pr][llo]      = f2b(p0);
        Pl[wid][pr][llo + 16] = f2b(p1);
      }
#pragma unroll
      for (int n = 0; n < 4; n++)
#pragma unroll
        for (int r = 0; r < 4; r++) O[m][n][r] *= sf[r];
    }
    short8 pf[4];
#pragma unroll
    for (int m = 0; m < 4; m++)
      pf[m] = *(const short8*)(&Pl[wid][m * 16 + llo][lhi * 8]);
#pragma unroll
    for (int n = 0; n < 4; n++) {
      const short8 vf = *(const short8*)(&Vt[n * 16 + llo][s0 + lhi * 8]);
#pragma unroll
      for (int m = 0; m < 4; m++) O[m][n] = mfma16(pf[m], vf, O[m][n]);
    }
  }

#pragma unroll
  for (int m = 0; m < 4; m++)
#pragma unroll
    for (int r = 0; r < 4; r++) {
      const int t = t0 + m * 16 + lhi * 4 + r;
      const float inv = 1.f / lrow[m][r];
      u16* orow = ctx + ((size_t)b * TT + t) * EE + h * 64;
#pragma unroll
      for (int n = 0; n < 4; n++)
        orow[n * 16 + llo] = f2b(O[m][n][r] * inv);
    }
}

// ---------------- launch ----------------

extern "C" void kernel_launch(void* const* d_in, const int* in_sizes, int n_in,
                              void* d_out, int out_size, void* d_ws, size_t ws_size,
                              hipStream_t stream) {
  const float* x   = (const float*)d_in[0];
  const float* Wq  = (const float*)d_in[1];
  const float* Wk  = (const float*)d_in[2];
  const float* Wv  = (const float*)d_in[3];
  const float* Wo  = (const float*)d_in[4];
  const float* bo  = (const float*)d_in[5];
  const float* g1  = (const float*)d_in[6];
  const float* be1 = (const float*)d_in[7];
  const float* g2  = (const float*)d_in[8];
  const float* be2 = (const float*)d_in[9];
  const float* W1  = (const float*)d_in[10];
  const float* b1  = (const float*)d_in[11];
  const float* W2  = (const float*)d_in[12];
  const float* b2  = (const float*)d_in[13];
  float* out = (float*)d_out;

  // workspace layout (~198 MB total)
  char* w = (char*)d_ws;
  u16* WqkvT = (u16*)w;                 w += (size_t)1536 * 512 * 2;   // 1.5 MB
  u16* WoT   = (u16*)w;                 w += (size_t)512 * 512 * 2;    // 0.5 MB
  u16* W1T   = (u16*)w;                 w += (size_t)2048 * 512 * 2;   // 2 MB
  u16* W2T   = (u16*)w;                 w += (size_t)512 * 2048 * 2;   // 2 MB
  u16* hbuf  = (u16*)w;                 w += (size_t)BT * EE * 2;      // 32 MB (h / h2)
  u16* ctxb  = (u16*)w;                 w += (size_t)BT * EE * 2;      // 32 MB
  u16* big   = (u16*)w;                                               // 128 MB (qkv / ff1)
  u16* qkvb = big;
  u16* ff1  = big;

  // 1. weight prep (bf16 + transpose to [N][K]), tiled/coalesced
  tconv_qkv<<<dim3(8, 1, 8), 256, 0, stream>>>(Wq, WqkvT, 0);
  tconv_qkv<<<dim3(8, 1, 8), 256, 0, stream>>>(Wk, WqkvT, 512);
  tconv_qkv<<<dim3(8, 1, 8), 256, 0, stream>>>(Wv, WqkvT, 1024);
  tconv<<<dim3(8, 8),  256, 0, stream>>>(Wo, 512,  WoT, 512);
  tconv<<<dim3(8, 32), 256, 0, stream>>>(W1, 2048, W1T, 512);
  tconv<<<dim3(32, 8), 256, 0, stream>>>(W2, 512,  W2T, 2048);

  // 2. LN1: h = ln(x)
  ln_fwd<<<BT / 4, 256, 0, stream>>>(x, g1, be1, hbuf);

  // 3. QKV: qkv = h @ WqkvT^T   [BT,1536] bf16  (grid 256*6)
  gemm3<false, false, false, true><<<1536, 512, 0, stream>>>(
      hbuf, WqkvT, nullptr, nullptr, qkvb, BT, 1536, 512);

  // 4. attention -> ctx [BT,512] bf16
  attn_fwd<<<BB * HH, 256, 0, stream>>>(qkvb, ctxb);

  // 5. proj: out1 = ctx @ Wo + bo + x  (fp32, into d_out)  (grid 256*2)
  gemm3<true, false, true, false><<<512, 512, 0, stream>>>(
      ctxb, WoT, bo, x, out, BT, 512, 512);

  // 6. LN2: h2 = ln(out1)  (reuse hbuf)
  ln_fwd<<<BT / 4, 256, 0, stream>>>(out, g2, be2, hbuf);

  // 7. FFN1: ff1 = relu(h2 @ W1 + b1)  [BT,2048] bf16  (grid 256*8)
  gemm3<true, true, false, true><<<2048, 512, 0, stream>>>(
      hbuf, W1T, b1, nullptr, ff1, BT, 2048, 512);

  // 8. FFN2: out = out1 + ff1 @ W2 + b2  (in-place residual on d_out)  (grid 256*2)
  gemm3<true, false, true, false><<<512, 512, 0, stream>>>(
      ff1, W2T, b2, out, out, BT, 512, 2048);
}